// Round 9
// baseline (247.619 us; speedup 1.0000x reference)
//
#include <hip/hip_runtime.h>

// GraphSAGE 3-layer forward: N=50000 nodes, E=800000 edges, F: 96->96->96->48
// out_i = relu( mean_{j in N(i)} h_j @ Wl + h_i @ Wr + b ), x3 layers.
//
// R9 = R8 resubmitted (R8 bench died to container infra failure, not kernel):
// fused_layer at 32 nodes / 384 threads per block:
//  - gather uses all 384 threads (was 192 of 256)
//  - cols staged in LDS at stride 68 dwords -> conflict-free (was 6-way, 506k conflicts)
//  - 6 waves cover 2 M-tiles x NT N-tiles in the MFMA phase
// Slotted adjacency build (R7) unchanged. 5 dispatches total.

#define NNODES 50000
#define NPAD   50176        // deg/h row allocation (covers tail-block OOB reads)
#define ZROW   50000        // sentinel row (all zeros) in each h buffer
#define NEDGES 800000
#define CAP    64           // per-node adjacency capacity (max deg ~40 w.h.p.)
#define CSTR   68           // LDS col stride in dwords (68%32=4 -> conflict-free)
#define EB 3125             // 800000/256 exact
#define CVT_N8 600000       // 50000*96/8
#define CB 2344             // ceil(600000/256)
#define WTN 46080           // 2*96*192 + 48*192
#define WB 180              // ceil(46080/256)

typedef __attribute__((ext_vector_type(8))) short bf16x8;
typedef __attribute__((ext_vector_type(4))) float f32x4;

__device__ inline unsigned short f2bf(float f) {
    unsigned int u = __float_as_uint(f);
    unsigned int r = (u + 0x7fffu + ((u >> 16) & 1u)) >> 16;   // RNE
    return (unsigned short)r;
}
__device__ inline float bf2f_lo(unsigned int u) { return __uint_as_float(u << 16); }
__device__ inline float bf2f_hi(unsigned int u) { return __uint_as_float(u & 0xffff0000u); }

// ---------------- pass 1: slotted adjacency build + converts + zero-rows ----------------
// blocks [0,EB): edges; [EB,EB+CB): x->bf16; next WB: WT prep; last 1: zero rows.
__global__ void build_cvt(const int* __restrict__ src, const int* __restrict__ dst,
                          int* __restrict__ deg, int* __restrict__ col,
                          const float* __restrict__ x, unsigned short* __restrict__ h0b,
                          unsigned short* __restrict__ h1b, unsigned short* __restrict__ h2b,
                          const float* __restrict__ Wl0, const float* __restrict__ Wr0,
                          const float* __restrict__ Wl1, const float* __restrict__ Wr1,
                          const float* __restrict__ Wl2, const float* __restrict__ Wr2,
                          unsigned short* __restrict__ WT0, unsigned short* __restrict__ WT1,
                          unsigned short* __restrict__ WT2) {
    int b = blockIdx.x;
    if (b < EB) {
        int e = b * 256 + threadIdx.x;                 // exact: EB*256 == NEDGES
        int d = dst[e];
        int r = atomicAdd(&deg[d], 1);
        if (r < CAP) col[(size_t)d * CAP + r] = src[e];
    } else if (b < EB + CB) {
        long long t = (long long)(b - EB) * 256 + threadIdx.x;
        if (t < CVT_N8) {
            const float4* p = reinterpret_cast<const float4*>(x + t * 8);
            float4 a = p[0], c = p[1];
            uint4 o;
            o.x = (unsigned)f2bf(a.x) | ((unsigned)f2bf(a.y) << 16);
            o.y = (unsigned)f2bf(a.z) | ((unsigned)f2bf(a.w) << 16);
            o.z = (unsigned)f2bf(c.x) | ((unsigned)f2bf(c.y) << 16);
            o.w = (unsigned)f2bf(c.z) | ((unsigned)f2bf(c.w) << 16);
            *reinterpret_cast<uint4*>(h0b + t * 8) = o;
        }
    } else if (b < EB + CB + WB) {
        int t = (b - EB - CB) * 256 + threadIdx.x;
        if (t >= WTN) return;
        const float* Wl; const float* Wr; unsigned short* WT; int fout; int u;
        if (t < 18432)      { Wl = Wl0; Wr = Wr0; WT = WT0; fout = 96; u = t; }
        else if (t < 36864) { Wl = Wl1; Wr = Wr1; WT = WT1; fout = 96; u = t - 18432; }
        else                { Wl = Wl2; Wr = Wr2; WT = WT2; fout = 48; u = t - 36864; }
        int j = u / 192;
        int k = u - j * 192;
        float v = (k < 96) ? Wl[k * fout + j] : Wr[(k - 96) * fout + j];
        WT[u] = f2bf(v);
    } else {
        // zero the sentinel rows: 3 buffers x 96 shorts = 36 uint4 stores
        int t = threadIdx.x;
        if (t < 36) {
            uint4 z = make_uint4(0, 0, 0, 0);
            unsigned short* base = (t < 12) ? h0b : (t < 24) ? h1b : h2b;
            int c = (t % 12) * 8;
            *reinterpret_cast<uint4*>(base + (size_t)ZROW * 96 + c) = z;
        }
    }
}

// ---------------- fused gather-mean + dual MFMA GEMM + bias + relu ----------------
// Block = 32 nodes, 384 threads (6 waves).
// Phase 1: stage 32*CAP col slots into LDS (stride CSTR, conflict-free),
//          sanitizing tail slots (slot>=deg -> ZROW).
// Phase 2: 384 threads = 32 nodes x 12 chunks gather-mean (8-wide, 8
//          outstanding 16B loads) into Asm[32][200].
// Phase 3: 6 waves x 2 M-tiles: wave w -> mt=w/3, nt in {w%3 (+3)}.
// A-frag (16x16x32 bf16): lane holds A[m=lane&15][k=(lane>>4)*8+0..7]
// B-frag: lane holds B[k=(lane>>4)*8+0..7][n=lane&15] -> WT[n][k] rows
// C/D: col=lane&15, row=(lane>>4)*4+reg  (verified layout, m89)
template <int NT, bool WRITE_BF16>
__global__ __launch_bounds__(384) void fused_layer(
    const unsigned short* __restrict__ hb,
    const int* __restrict__ deg, const int* __restrict__ col,
    const unsigned short* __restrict__ WT,   // [16*NT][192]
    const float* __restrict__ bias,          // [16*NT]
    unsigned short* __restrict__ out_bf, float* __restrict__ out_f) {
    __shared__ unsigned short Asm[32][200];
    __shared__ int cols[32 * CSTR];
    const int i0 = blockIdx.x * 32;
    const int t = threadIdx.x;

    // ---- phase 1: stage + sanitize adjacency (2048 ints, strided re-layout) ----
    for (int q = t * 4; q < 32 * CAP; q += 384 * 4) {
        int node = q >> 6;                   // CAP=64
        int slot = q & 63;
        int4 v = *reinterpret_cast<const int4*>(col + (size_t)(i0 + node) * CAP + slot);
        int d = deg[i0 + node];
        v.x = (slot + 0 < d) ? v.x : ZROW;
        v.y = (slot + 1 < d) ? v.y : ZROW;
        v.z = (slot + 2 < d) ? v.z : ZROW;
        v.w = (slot + 3 < d) ? v.w : ZROW;
        *reinterpret_cast<int4*>(&cols[node * CSTR + slot]) = v;
    }
    __syncthreads();

    // ---- phase 2: gather-mean (all 384 threads) ----
    {
        const int nl = t / 12;               // 0..31
        const int c = (t - nl * 12) * 8;
        const int node = i0 + nl;
        const int d = (node < NNODES) ? deg[node] : 0;
        const int pd = (d + 7) & ~7;
        float a0 = 0.f, a1 = 0.f, a2 = 0.f, a3 = 0.f, a4 = 0.f, a5 = 0.f, a6 = 0.f, a7 = 0.f;
        for (int j = 0; j < pd; j += 8) {
            int4 ca = *reinterpret_cast<const int4*>(&cols[nl * CSTR + j]);
            int4 cb = *reinterpret_cast<const int4*>(&cols[nl * CSTR + j + 4]);
            uint4 u0 = *reinterpret_cast<const uint4*>(hb + (size_t)ca.x * 96 + c);
            uint4 u1 = *reinterpret_cast<const uint4*>(hb + (size_t)ca.y * 96 + c);
            uint4 u2 = *reinterpret_cast<const uint4*>(hb + (size_t)ca.z * 96 + c);
            uint4 u3 = *reinterpret_cast<const uint4*>(hb + (size_t)ca.w * 96 + c);
            uint4 u4 = *reinterpret_cast<const uint4*>(hb + (size_t)cb.x * 96 + c);
            uint4 u5 = *reinterpret_cast<const uint4*>(hb + (size_t)cb.y * 96 + c);
            uint4 u6 = *reinterpret_cast<const uint4*>(hb + (size_t)cb.z * 96 + c);
            uint4 u7 = *reinterpret_cast<const uint4*>(hb + (size_t)cb.w * 96 + c);
            a0 += bf2f_lo(u0.x) + bf2f_lo(u1.x) + bf2f_lo(u2.x) + bf2f_lo(u3.x)
                + bf2f_lo(u4.x) + bf2f_lo(u5.x) + bf2f_lo(u6.x) + bf2f_lo(u7.x);
            a1 += bf2f_hi(u0.x) + bf2f_hi(u1.x) + bf2f_hi(u2.x) + bf2f_hi(u3.x)
                + bf2f_hi(u4.x) + bf2f_hi(u5.x) + bf2f_hi(u6.x) + bf2f_hi(u7.x);
            a2 += bf2f_lo(u0.y) + bf2f_lo(u1.y) + bf2f_lo(u2.y) + bf2f_lo(u3.y)
                + bf2f_lo(u4.y) + bf2f_lo(u5.y) + bf2f_lo(u6.y) + bf2f_lo(u7.y);
            a3 += bf2f_hi(u0.y) + bf2f_hi(u1.y) + bf2f_hi(u2.y) + bf2f_hi(u3.y)
                + bf2f_hi(u4.y) + bf2f_hi(u5.y) + bf2f_hi(u6.y) + bf2f_hi(u7.y);
            a4 += bf2f_lo(u0.z) + bf2f_lo(u1.z) + bf2f_lo(u2.z) + bf2f_lo(u3.z)
                + bf2f_lo(u4.z) + bf2f_lo(u5.z) + bf2f_lo(u6.z) + bf2f_lo(u7.z);
            a5 += bf2f_hi(u0.z) + bf2f_hi(u1.z) + bf2f_hi(u2.z) + bf2f_hi(u3.z)
                + bf2f_hi(u4.z) + bf2f_hi(u5.z) + bf2f_hi(u6.z) + bf2f_hi(u7.z);
            a6 += bf2f_lo(u0.w) + bf2f_lo(u1.w) + bf2f_lo(u2.w) + bf2f_lo(u3.w)
                + bf2f_lo(u4.w) + bf2f_lo(u5.w) + bf2f_lo(u6.w) + bf2f_lo(u7.w);
            a7 += bf2f_hi(u0.w) + bf2f_hi(u1.w) + bf2f_hi(u2.w) + bf2f_hi(u3.w)
                + bf2f_hi(u4.w) + bf2f_hi(u5.w) + bf2f_hi(u6.w) + bf2f_hi(u7.w);
        }
        float inv = (d > 0) ? 1.0f / (float)d : 0.0f;
        uint4 o;
        o.x = (unsigned)f2bf(a0 * inv) | ((unsigned)f2bf(a1 * inv) << 16);
        o.y = (unsigned)f2bf(a2 * inv) | ((unsigned)f2bf(a3 * inv) << 16);
        o.z = (unsigned)f2bf(a4 * inv) | ((unsigned)f2bf(a5 * inv) << 16);
        o.w = (unsigned)f2bf(a6 * inv) | ((unsigned)f2bf(a7 * inv) << 16);
        *reinterpret_cast<uint4*>(&Asm[nl][c]) = o;
    }
    __syncthreads();

    // ---- phase 3: MFMA (6 waves, 2 M-tiles x NT N-tiles) ----
    const int wave = t >> 6;                 // 0..5
    const int lane = t & 63;
    const int mt = (wave >= 3) ? 1 : 0;
    const int w3 = wave - mt * 3;            // 0..2
    const int m = lane & 15;
    const int kq = (lane >> 4) * 8;
    const int row0 = i0 + mt * 16;

    bf16x8 afr[6];
#pragma unroll
    for (int kk = 0; kk < 3; ++kk)
        afr[kk] = *reinterpret_cast<const bf16x8*>(&Asm[mt * 16 + m][kq + kk * 32]);
    const unsigned short* hrow = hb + (size_t)(row0 + m) * 96 + kq;
#pragma unroll
    for (int kk = 0; kk < 3; ++kk)
        afr[3 + kk] = *reinterpret_cast<const bf16x8*>(hrow + kk * 32);

    const int r0 = (lane >> 4) * 4;
    constexpr int REP = (NT + 2) / 3;        // 2 for NT=6, 1 for NT=3
#pragma unroll
    for (int rep = 0; rep < REP; ++rep) {
        int nt = w3 + rep * 3;
        f32x4 acc = {0.f, 0.f, 0.f, 0.f};
        const unsigned short* wrow = WT + (size_t)(nt * 16 + m) * 192 + kq;
#pragma unroll
        for (int kk = 0; kk < 6; ++kk) {
            bf16x8 bfr = *reinterpret_cast<const bf16x8*>(wrow + kk * 32);
            acc = __builtin_amdgcn_mfma_f32_16x16x32_bf16(afr[kk], bfr, acc, 0, 0, 0);
        }
        int colj = nt * 16 + m;
        float bv = bias[colj];
#pragma unroll
        for (int r = 0; r < 4; ++r) {
            float v = fmaxf(acc[r] + bv, 0.0f);
            int row = row0 + r0 + r;
            if (row < NNODES) {
                size_t oi = (size_t)row * (16 * NT) + colj;
                if (WRITE_BF16) out_bf[oi] = f2bf(v);
                else            out_f[oi] = v;
            }
        }
    }
}

extern "C" void kernel_launch(void* const* d_in, const int* in_sizes, int n_in,
                              void* d_out, int out_size, void* d_ws, size_t ws_size,
                              hipStream_t stream) {
    const float* x   = (const float*)d_in[0];
    const int*   ei  = (const int*)d_in[1];   // [2, E]: row0 = src, row1 = dst
    const float* Wl0 = (const float*)d_in[2];
    const float* Wr0 = (const float*)d_in[3];
    const float* b0  = (const float*)d_in[4];
    const float* Wl1 = (const float*)d_in[5];
    const float* Wr1 = (const float*)d_in[6];
    const float* b1  = (const float*)d_in[7];
    const float* Wl2 = (const float*)d_in[8];
    const float* Wr2 = (const float*)d_in[9];
    const float* b2  = (const float*)d_in[10];
    float* out = (float*)d_out;

    const int* src = ei;
    const int* dst = ei + NEDGES;

    // workspace layout (deg/col/h sized NPAD rows so tail-block reads stay in-bounds)
    char* p = (char*)d_ws;
    int* deg = (int*)p;                  p += (size_t)NPAD * 4;
    int* col = (int*)p;                  p += (size_t)NPAD * CAP * 4;   // 12.8 MB
    unsigned short* WT0 = (unsigned short*)p; p += 96 * 192 * 2;
    unsigned short* WT1 = (unsigned short*)p; p += 96 * 192 * 2;
    unsigned short* WT2 = (unsigned short*)p; p += 48 * 192 * 2;
    unsigned short* h0b = (unsigned short*)p; p += (size_t)NPAD * 96 * 2;
    unsigned short* h1b = (unsigned short*)p; p += (size_t)NPAD * 96 * 2;
    unsigned short* h2b = (unsigned short*)p; p += (size_t)NPAD * 96 * 2;

    // ---- adjacency build + converts (one grid) ----
    hipMemsetAsync(deg, 0, (size_t)NPAD * sizeof(int), stream);
    build_cvt<<<EB + CB + WB + 1, 256, 0, stream>>>(
        src, dst, deg, col, x, h0b, h1b, h2b,
        Wl0, Wr0, Wl1, Wr1, Wl2, Wr2, WT0, WT1, WT2);

    // ---- layers (fused gather + MFMA), 32 nodes / 384 threads per block ----
    const int LB = (NNODES + 31) / 32;   // 1563
    fused_layer<6, true><<<LB, 384, 0, stream>>>(h0b, deg, col, WT0, b0, h1b, nullptr);
    fused_layer<6, true><<<LB, 384, 0, stream>>>(h1b, deg, col, WT1, b1, h2b, nullptr);
    fused_layer<3, false><<<LB, 384, 0, stream>>>(h2b, deg, col, WT2, b2, nullptr, out);
}

// Round 10
// 238.934 us; speedup vs baseline: 1.0363x; 1.0363x over previous
//
#include <hip/hip_runtime.h>

// GraphSAGE 3-layer forward: N=50000 nodes, E=800000 edges, F: 96->96->96->48
// out_i = relu( mean_{j in N(i)} h_j @ Wl + h_i @ Wr + b ), x3 layers.
//
// R10: h stored as 3 feature-planes of 32 (3.2 MB each, fits 4 MB per-XCD L2).
// Gather runs 3 temporal phases, phase p reads only plane p; all blocks are
// co-resident (3125 blocks, 8/CU) so phases align chip-wide -> L2-resident
// gathers. 256 threads = 16 nodes x 4 chunks x 4 neighbor-quarters; quarter
// partials reduced via __shfl_down (same-wave by construction). Back to R7's
// 16-node/256-thread shape (R8/R9's 384-thread blocks regressed: occupancy).

#define NNODES 50000
#define NPAD   50176        // plane row allocation
#define ZROW   50000        // sentinel row (all zeros) in each plane
#define NEDGES 800000
#define CAP    64           // per-node adjacency capacity (max deg ~40 w.h.p.)
#define CSTR   68           // LDS col stride in dwords (68%32=4 -> ~conflict-free)
#define PL     ((size_t)NPAD * 32)   // shorts per plane
#define EB 3125             // 800000/256 exact
#define CVT_N8 600000       // 50000*96/8
#define CB 2344             // ceil(600000/256)
#define WTN 46080           // 2*96*192 + 48*192
#define WB 180              // ceil(46080/256)

typedef __attribute__((ext_vector_type(8))) short bf16x8;
typedef __attribute__((ext_vector_type(4))) float f32x4;

__device__ inline unsigned short f2bf(float f) {
    unsigned int u = __float_as_uint(f);
    unsigned int r = (u + 0x7fffu + ((u >> 16) & 1u)) >> 16;   // RNE
    return (unsigned short)r;
}
__device__ inline float bf2f_lo(unsigned int u) { return __uint_as_float(u << 16); }
__device__ inline float bf2f_hi(unsigned int u) { return __uint_as_float(u & 0xffff0000u); }

// ---------------- pass 1: slotted adjacency build + converts + zero-rows ----------------
// blocks [0,EB): edges; [EB,EB+CB): x->bf16 planes; next WB: WT prep; last 1: zero rows.
__global__ void build_cvt(const int* __restrict__ src, const int* __restrict__ dst,
                          int* __restrict__ deg, int* __restrict__ col,
                          const float* __restrict__ x, unsigned short* __restrict__ h0b,
                          unsigned short* __restrict__ h1b, unsigned short* __restrict__ h2b,
                          const float* __restrict__ Wl0, const float* __restrict__ Wr0,
                          const float* __restrict__ Wl1, const float* __restrict__ Wr1,
                          const float* __restrict__ Wl2, const float* __restrict__ Wr2,
                          unsigned short* __restrict__ WT0, unsigned short* __restrict__ WT1,
                          unsigned short* __restrict__ WT2) {
    int b = blockIdx.x;
    if (b < EB) {
        int e = b * 256 + threadIdx.x;                 // exact: EB*256 == NEDGES
        int d = dst[e];
        int r = atomicAdd(&deg[d], 1);
        if (r < CAP) col[(size_t)d * CAP + r] = src[e];
    } else if (b < EB + CB) {
        long long t = (long long)(b - EB) * 256 + threadIdx.x;
        if (t < CVT_N8) {
            int n = (int)(t / 12);
            int c = (int)(t - (long long)n * 12);      // 8-feat chunk 0..11
            int pp = c >> 2;                           // plane
            int c4 = c & 3;
            const float4* p4 = reinterpret_cast<const float4*>(x + (size_t)n * 96 + c * 8);
            float4 a = p4[0], cc = p4[1];
            uint4 o;
            o.x = (unsigned)f2bf(a.x) | ((unsigned)f2bf(a.y) << 16);
            o.y = (unsigned)f2bf(a.z) | ((unsigned)f2bf(a.w) << 16);
            o.z = (unsigned)f2bf(cc.x) | ((unsigned)f2bf(cc.y) << 16);
            o.w = (unsigned)f2bf(cc.z) | ((unsigned)f2bf(cc.w) << 16);
            *reinterpret_cast<uint4*>(h0b + (size_t)pp * PL + (size_t)n * 32 + c4 * 8) = o;
        }
    } else if (b < EB + CB + WB) {
        int t = (b - EB - CB) * 256 + threadIdx.x;
        if (t >= WTN) return;
        const float* Wl; const float* Wr; unsigned short* WT; int fout; int u;
        if (t < 18432)      { Wl = Wl0; Wr = Wr0; WT = WT0; fout = 96; u = t; }
        else if (t < 36864) { Wl = Wl1; Wr = Wr1; WT = WT1; fout = 96; u = t - 18432; }
        else                { Wl = Wl2; Wr = Wr2; WT = WT2; fout = 48; u = t - 36864; }
        int j = u / 192;
        int k = u - j * 192;
        float v = (k < 96) ? Wl[k * fout + j] : Wr[(k - 96) * fout + j];
        WT[u] = f2bf(v);
    } else {
        // zero the sentinel rows: 3 buffers x 3 planes x 64B = 36 uint4 stores
        int t = threadIdx.x;
        if (t < 36) {
            uint4 z = make_uint4(0, 0, 0, 0);
            unsigned short* base = (t < 12) ? h0b : (t < 24) ? h1b : h2b;
            int u = t % 12;
            int pp = u >> 2;            // plane
            int s = u & 3;              // 16B chunk within 64B row
            *reinterpret_cast<uint4*>(base + (size_t)pp * PL + (size_t)ZROW * 32 + s * 8) = z;
        }
    }
}

// ---------------- fused gather-mean + dual MFMA GEMM + bias + relu ----------------
// Block = 16 nodes, 256 threads (4 waves).
// Stage 16*CAP col slots into LDS (sanitized, stride CSTR). Then 3 plane
// phases: thread (node, chunk4, quarter) gathers its quarter's neighbor slots
// from plane p only (8 outstanding 16B loads); quarter partials reduced with
// __shfl_down(8)/(4) (lanes node*16+q*4+c4 are same-wave); q==0 lanes write
// the mean chunk to Asm. Then 4 waves run K=192 [mean|h] @ [Wl;Wr] MFMA.
// A-frag (16x16x32 bf16): lane holds A[m=lane&15][k=(lane>>4)*8+0..7]
// B-frag: lane holds B[k=(lane>>4)*8+0..7][n=lane&15] -> WT[n][k] rows
// C/D: col=lane&15, row=(lane>>4)*4+reg  (verified layout, m89)
template <int NT, bool WRITE_BF16>
__global__ __launch_bounds__(256) void fused_layer(
    const unsigned short* __restrict__ hb,   // base of plane 0
    const int* __restrict__ deg, const int* __restrict__ col,
    const unsigned short* __restrict__ WT,   // [16*NT][192]
    const float* __restrict__ bias,          // [16*NT]
    unsigned short* __restrict__ out_bf,     // base of next layer's plane 0
    float* __restrict__ out_f) {
    __shared__ unsigned short Asm[16][200];
    __shared__ int cols[16 * CSTR];
    const int i0 = blockIdx.x * 16;
    const int t = threadIdx.x;

    // ---- stage + sanitize adjacency (1024 ints, 4 per thread) ----
    {
        int q = t * 4;
        int node = q >> 6;                   // CAP=64
        int slot = q & 63;
        int4 v = *reinterpret_cast<const int4*>(col + (size_t)(i0 + node) * CAP + slot);
        int d = deg[i0 + node];
        v.x = (slot + 0 < d) ? v.x : ZROW;
        v.y = (slot + 1 < d) ? v.y : ZROW;
        v.z = (slot + 2 < d) ? v.z : ZROW;
        v.w = (slot + 3 < d) ? v.w : ZROW;
        *reinterpret_cast<int4*>(&cols[node * CSTR + slot]) = v;
    }
    __syncthreads();

    // ---- gather-mean in 3 plane phases ----
    {
        const int node = t >> 4;             // 0..15
        const int r = t & 15;
        const int c4 = r & 3;                // 8-feat chunk within plane
        const int q = r >> 2;                // neighbor-list quarter
        const int coff = c4 * 8;
        const int d = deg[i0 + node];
        const int pd = (d + 7) & ~7;
        const float inv = (d > 0) ? 1.0f / (float)d : 0.0f;

#pragma unroll
        for (int pp = 0; pp < 3; ++pp) {
            const unsigned short* __restrict__ plane = hb + (size_t)pp * PL;
            float a0 = 0.f, a1 = 0.f, a2 = 0.f, a3 = 0.f;
            float a4 = 0.f, a5 = 0.f, a6 = 0.f, a7 = 0.f;
            // quarter q handles slots {q*8 + 32k}: disjoint union covers [0,64)
            for (int j = q * 8; j < pd; j += 32) {
                int4 ca = *reinterpret_cast<const int4*>(&cols[node * CSTR + j]);
                int4 cb = *reinterpret_cast<const int4*>(&cols[node * CSTR + j + 4]);
                uint4 u0 = *reinterpret_cast<const uint4*>(plane + (size_t)ca.x * 32 + coff);
                uint4 u1 = *reinterpret_cast<const uint4*>(plane + (size_t)ca.y * 32 + coff);
                uint4 u2 = *reinterpret_cast<const uint4*>(plane + (size_t)ca.z * 32 + coff);
                uint4 u3 = *reinterpret_cast<const uint4*>(plane + (size_t)ca.w * 32 + coff);
                uint4 u4 = *reinterpret_cast<const uint4*>(plane + (size_t)cb.x * 32 + coff);
                uint4 u5 = *reinterpret_cast<const uint4*>(plane + (size_t)cb.y * 32 + coff);
                uint4 u6 = *reinterpret_cast<const uint4*>(plane + (size_t)cb.z * 32 + coff);
                uint4 u7 = *reinterpret_cast<const uint4*>(plane + (size_t)cb.w * 32 + coff);
                a0 += bf2f_lo(u0.x) + bf2f_lo(u1.x) + bf2f_lo(u2.x) + bf2f_lo(u3.x)
                    + bf2f_lo(u4.x) + bf2f_lo(u5.x) + bf2f_lo(u6.x) + bf2f_lo(u7.x);
                a1 += bf2f_hi(u0.x) + bf2f_hi(u1.x) + bf2f_hi(u2.x) + bf2f_hi(u3.x)
                    + bf2f_hi(u4.x) + bf2f_hi(u5.x) + bf2f_hi(u6.x) + bf2f_hi(u7.x);
                a2 += bf2f_lo(u0.y) + bf2f_lo(u1.y) + bf2f_lo(u2.y) + bf2f_lo(u3.y)
                    + bf2f_lo(u4.y) + bf2f_lo(u5.y) + bf2f_lo(u6.y) + bf2f_lo(u7.y);
                a3 += bf2f_hi(u0.y) + bf2f_hi(u1.y) + bf2f_hi(u2.y) + bf2f_hi(u3.y)
                    + bf2f_hi(u4.y) + bf2f_hi(u5.y) + bf2f_hi(u6.y) + bf2f_hi(u7.y);
                a4 += bf2f_lo(u0.z) + bf2f_lo(u1.z) + bf2f_lo(u2.z) + bf2f_lo(u3.z)
                    + bf2f_lo(u4.z) + bf2f_lo(u5.z) + bf2f_lo(u6.z) + bf2f_lo(u7.z);
                a5 += bf2f_hi(u0.z) + bf2f_hi(u1.z) + bf2f_hi(u2.z) + bf2f_hi(u3.z)
                    + bf2f_hi(u4.z) + bf2f_hi(u5.z) + bf2f_hi(u6.z) + bf2f_hi(u7.z);
                a6 += bf2f_lo(u0.w) + bf2f_lo(u1.w) + bf2f_lo(u2.w) + bf2f_lo(u3.w)
                    + bf2f_lo(u4.w) + bf2f_lo(u5.w) + bf2f_lo(u6.w) + bf2f_lo(u7.w);
                a7 += bf2f_hi(u0.w) + bf2f_hi(u1.w) + bf2f_hi(u2.w) + bf2f_hi(u3.w)
                    + bf2f_hi(u4.w) + bf2f_hi(u5.w) + bf2f_hi(u6.w) + bf2f_hi(u7.w);
            }
            // reduce quarters: lanes node*16 + q*4 + c4, q=0..3 -> same wave
            a0 += __shfl_down(a0, 8); a1 += __shfl_down(a1, 8);
            a2 += __shfl_down(a2, 8); a3 += __shfl_down(a3, 8);
            a4 += __shfl_down(a4, 8); a5 += __shfl_down(a5, 8);
            a6 += __shfl_down(a6, 8); a7 += __shfl_down(a7, 8);
            a0 += __shfl_down(a0, 4); a1 += __shfl_down(a1, 4);
            a2 += __shfl_down(a2, 4); a3 += __shfl_down(a3, 4);
            a4 += __shfl_down(a4, 4); a5 += __shfl_down(a5, 4);
            a6 += __shfl_down(a6, 4); a7 += __shfl_down(a7, 4);
            if (q == 0) {
                uint4 o;
                o.x = (unsigned)f2bf(a0 * inv) | ((unsigned)f2bf(a1 * inv) << 16);
                o.y = (unsigned)f2bf(a2 * inv) | ((unsigned)f2bf(a3 * inv) << 16);
                o.z = (unsigned)f2bf(a4 * inv) | ((unsigned)f2bf(a5 * inv) << 16);
                o.w = (unsigned)f2bf(a6 * inv) | ((unsigned)f2bf(a7 * inv) << 16);
                *reinterpret_cast<uint4*>(&Asm[node][pp * 32 + coff]) = o;
            }
        }
    }
    __syncthreads();

    // ---- MFMA (4 waves) ----
    const int wave = t >> 6;
    const int lane = t & 63;
    const int m = lane & 15;
    const int kq = (lane >> 4) * 8;

    bf16x8 afr[6];
#pragma unroll
    for (int kk = 0; kk < 3; ++kk)
        afr[kk] = *reinterpret_cast<const bf16x8*>(&Asm[m][kq + kk * 32]);
#pragma unroll
    for (int kk = 0; kk < 3; ++kk)   // h feature kk*32+kq -> plane kk, offset kq
        afr[3 + kk] = *reinterpret_cast<const bf16x8*>(
            hb + (size_t)kk * PL + (size_t)(i0 + m) * 32 + kq);

    const int r0 = (lane >> 4) * 4;
    for (int nt = wave; nt < NT; nt += 4) {
        f32x4 acc = {0.f, 0.f, 0.f, 0.f};
        const unsigned short* wrow = WT + (size_t)(nt * 16 + m) * 192 + kq;
#pragma unroll
        for (int kk = 0; kk < 6; ++kk) {
            bf16x8 bfr = *reinterpret_cast<const bf16x8*>(wrow + kk * 32);
            acc = __builtin_amdgcn_mfma_f32_16x16x32_bf16(afr[kk], bfr, acc, 0, 0, 0);
        }
        int colj = nt * 16 + m;
        float bv = bias[colj];
#pragma unroll
        for (int r = 0; r < 4; ++r) {
            float v = fmaxf(acc[r] + bv, 0.0f);
            int row = i0 + r0 + r;
            if (WRITE_BF16) {
                out_bf[(size_t)(colj >> 5) * PL + (size_t)row * 32 + (colj & 31)] = f2bf(v);
            } else {
                out_f[(size_t)row * (16 * NT) + colj] = v;
            }
        }
    }
}

extern "C" void kernel_launch(void* const* d_in, const int* in_sizes, int n_in,
                              void* d_out, int out_size, void* d_ws, size_t ws_size,
                              hipStream_t stream) {
    const float* x   = (const float*)d_in[0];
    const int*   ei  = (const int*)d_in[1];   // [2, E]: row0 = src, row1 = dst
    const float* Wl0 = (const float*)d_in[2];
    const float* Wr0 = (const float*)d_in[3];
    const float* b0  = (const float*)d_in[4];
    const float* Wl1 = (const float*)d_in[5];
    const float* Wr1 = (const float*)d_in[6];
    const float* b1  = (const float*)d_in[7];
    const float* Wl2 = (const float*)d_in[8];
    const float* Wr2 = (const float*)d_in[9];
    const float* b2  = (const float*)d_in[10];
    float* out = (float*)d_out;

    const int* src = ei;
    const int* dst = ei + NEDGES;

    // workspace layout (h buffers = 3 planes of [NPAD][32] bf16 each)
    char* p = (char*)d_ws;
    int* deg = (int*)p;                  p += (size_t)NPAD * 4;
    int* col = (int*)p;                  p += (size_t)NPAD * CAP * 4;   // 12.8 MB
    unsigned short* WT0 = (unsigned short*)p; p += 96 * 192 * 2;
    unsigned short* WT1 = (unsigned short*)p; p += 96 * 192 * 2;
    unsigned short* WT2 = (unsigned short*)p; p += 48 * 192 * 2;
    unsigned short* h0b = (unsigned short*)p; p += 3 * PL * 2;
    unsigned short* h1b = (unsigned short*)p; p += 3 * PL * 2;
    unsigned short* h2b = (unsigned short*)p; p += 3 * PL * 2;

    // ---- adjacency build + converts (one grid) ----
    hipMemsetAsync(deg, 0, (size_t)NPAD * sizeof(int), stream);
    build_cvt<<<EB + CB + WB + 1, 256, 0, stream>>>(
        src, dst, deg, col, x, h0b, h1b, h2b,
        Wl0, Wr0, Wl1, Wr1, Wl2, Wr2, WT0, WT1, WT2);

    // ---- layers (fused gather + MFMA), 16 nodes / 256 threads per block ----
    const int LB = NNODES / 16;   // 3125 exact
    fused_layer<6, true><<<LB, 256, 0, stream>>>(h0b, deg, col, WT0, b0, h1b, nullptr);
    fused_layer<6, true><<<LB, 256, 0, stream>>>(h1b, deg, col, WT1, b1, h2b, nullptr);
    fused_layer<3, false><<<LB, 256, 0, stream>>>(h2b, deg, col, WT2, b2, nullptr, out);
}